// Round 1
// baseline (772.508 us; speedup 1.0000x reference)
//
#include <hip/hip_runtime.h>

// FamilyMLPLinear: per-class tiny MLP (16 -> 4 -> 1) over [B=512, C=17929].
// Memory-bound: x is 587 MB streamed once; weights ~5 MB cache-resident.
// One thread per class, KB batches per thread to amortize W1 register load.

#define NUM_MODELS 16
#define HIDDEN 4
#define BATCH 512
#define NUM_CLASSES 17929
#define KB 16   // batches handled per thread
#define CT 256  // classes per block (== blockDim.x)

__global__ __launch_bounds__(CT) void FamilyMLPLinear_kernel(
    const float* __restrict__ x,    // [M, B, C]
    const float* __restrict__ W1,   // [C, H, M]
    const float* __restrict__ b1,   // [C, H]
    const float* __restrict__ W2,   // [C, H]
    const float* __restrict__ b2,   // [C]
    float* __restrict__ out)        // [B, C]
{
    const int c = blockIdx.x * CT + threadIdx.x;
    if (c >= NUM_CLASSES) return;
    const int b0 = blockIdx.y * KB;

    // ---- per-class weights into registers (vectorized, 16B-aligned) ----
    float w1[HIDDEN][NUM_MODELS];
    const float4* W1v = (const float4*)(W1 + (size_t)c * (HIDDEN * NUM_MODELS));
    #pragma unroll
    for (int j = 0; j < HIDDEN; ++j) {
        #pragma unroll
        for (int q = 0; q < NUM_MODELS / 4; ++q) {
            float4 v = W1v[j * (NUM_MODELS / 4) + q];
            w1[j][q * 4 + 0] = v.x;
            w1[j][q * 4 + 1] = v.y;
            w1[j][q * 4 + 2] = v.z;
            w1[j][q * 4 + 3] = v.w;
        }
    }
    const float4 b1v = *(const float4*)(b1 + (size_t)c * HIDDEN);
    const float bias1[HIDDEN] = {b1v.x, b1v.y, b1v.z, b1v.w};
    const float4 w2v = *(const float4*)(W2 + (size_t)c * HIDDEN);
    const float w2[HIDDEN] = {w2v.x, w2v.y, w2v.z, w2v.w};
    const float bias2 = b2[c];

    const size_t BC = (size_t)BATCH * NUM_CLASSES;

    #pragma unroll 1
    for (int bi = 0; bi < KB; ++bi) {
        const int b = b0 + bi;
        const float* xp = x + (size_t)b * NUM_CLASSES + c;

        // 16 coalesced x loads (each a contiguous 256B wave access)
        float xv[NUM_MODELS];
        #pragma unroll
        for (int m = 0; m < NUM_MODELS; ++m)
            xv[m] = xp[(size_t)m * BC];

        float acc = bias2;
        #pragma unroll
        for (int j = 0; j < HIDDEN; ++j) {
            float h = bias1[j];
            #pragma unroll
            for (int m = 0; m < NUM_MODELS; ++m)
                h = fmaf(xv[m], w1[j][m], h);
            h = fmaxf(h, 0.0f);
            acc = fmaf(h, w2[j], acc);
        }
        out[(size_t)b * NUM_CLASSES + c] = acc;
    }
}

extern "C" void kernel_launch(void* const* d_in, const int* in_sizes, int n_in,
                              void* d_out, int out_size, void* d_ws, size_t ws_size,
                              hipStream_t stream) {
    const float* x  = (const float*)d_in[0];
    const float* W1 = (const float*)d_in[1];
    const float* b1 = (const float*)d_in[2];
    const float* W2 = (const float*)d_in[3];
    const float* b2 = (const float*)d_in[4];
    float* out = (float*)d_out;

    dim3 grid((NUM_CLASSES + CT - 1) / CT, BATCH / KB);
    FamilyMLPLinear_kernel<<<grid, CT, 0, stream>>>(x, W1, b1, W2, b2, out);
}